// Round 6
// baseline (354.256 us; speedup 1.0000x reference)
//
#include <hip/hip_runtime.h>
#include <hip/hip_fp16.h>
#include <math.h>

typedef _Float16 f16;
typedef f16 f16x2 __attribute__((ext_vector_type(2)));
typedef f16 f16x4 __attribute__((ext_vector_type(4)));
typedef f16 f16x8 __attribute__((ext_vector_type(8)));
typedef float f32x4_t __attribute__((ext_vector_type(4)));

__device__ __forceinline__ float sigmoidf(float x) {
  return 1.0f / (1.0f + __expf(-x));
}

// direct-to-LDS 16B copy: LDS dest = wave-uniform base + lane*16
#define GLDS16(gp, lp)                                                     \
  __builtin_amdgcn_global_load_lds(                                        \
      (const __attribute__((address_space(1))) void*)(gp),                 \
      (__attribute__((address_space(3))) void*)(lp), 16, 0, 0)

__global__ void zero_ints(int* __restrict__ p, int n) {
  int i = blockIdx.x * blockDim.x + threadIdx.x;
  if (i < n) p[i] = 0;
}

// ===========================================================================
// CSR build v2 (N <= 65536): 256-node radix buckets.
//   bucket b = dst >> 8 ; bcntP/gcurP padded stride 16 ints (1 line/bucket)
// ===========================================================================
__global__ void bucket_hist(const int* __restrict__ dst, int* __restrict__ bcntP,
                            int E, int NB) {
  __shared__ int h[256];
  for (int i = threadIdx.x; i < NB; i += 256) h[i] = 0;
  __syncthreads();
  int base = (blockIdx.x * 256 + threadIdx.x) * 4;
  if (base + 3 < E) {
    int4 d = *(const int4*)&dst[base];
    atomicAdd(&h[d.x >> 8], 1);
    atomicAdd(&h[d.y >> 8], 1);
    atomicAdd(&h[d.z >> 8], 1);
    atomicAdd(&h[d.w >> 8], 1);
  } else {
    for (int e = base; e < E; ++e) atomicAdd(&h[dst[e] >> 8], 1);
  }
  __syncthreads();
  for (int i = threadIdx.x; i < NB; i += 256)
    if (h[i]) atomicAdd(&bcntP[i * 16], h[i]);
}

// single block, 256 threads: exclusive scan of NB bucket counts
__global__ __launch_bounds__(256) void bucket_scan(const int* __restrict__ bcntP,
                                                   int* __restrict__ bbases,
                                                   int* __restrict__ gcurP, int NB) {
  __shared__ int wsum[4];
  const int tid = threadIdx.x, lane = tid & 63, wid = tid >> 6;
  int v = (tid < NB) ? bcntP[tid * 16] : 0;
  int x = v;
  #pragma unroll
  for (int d = 1; d < 64; d <<= 1) { int y = __shfl_up(x, d); if (lane >= d) x += y; }
  if (lane == 63) wsum[wid] = x;
  __syncthreads();
  if (wid == 0 && lane < 4) {
    int ws = wsum[lane];
    #pragma unroll
    for (int d = 1; d < 4; d <<= 1) { int y = __shfl_up(ws, d); if (lane >= d) ws += y; }
    wsum[lane] = ws;
  }
  __syncthreads();
  int excl = x - v + (wid ? wsum[wid - 1] : 0);
  if (tid < NB) { bbases[tid] = excl; gcurP[tid * 16] = excl; }
  if (tid == NB - 1) bbases[NB] = excl + v;
}

// scatter (src, dst&255) records into bucket bins
__global__ void partition_k(const int* __restrict__ src, const int* __restrict__ dst,
                            int* __restrict__ gcurP, unsigned int* __restrict__ bin,
                            int E) {
  int base = (blockIdx.x * 256 + threadIdx.x) * 4;
  if (base + 3 < E) {
    int4 d = *(const int4*)&dst[base];
    int4 s = *(const int4*)&src[base];
    int p0 = atomicAdd(&gcurP[(d.x >> 8) * 16], 1);
    int p1 = atomicAdd(&gcurP[(d.y >> 8) * 16], 1);
    int p2 = atomicAdd(&gcurP[(d.z >> 8) * 16], 1);
    int p3 = atomicAdd(&gcurP[(d.w >> 8) * 16], 1);
    bin[p0] = (unsigned int)s.x | ((unsigned int)(d.x & 255) << 16);
    bin[p1] = (unsigned int)s.y | ((unsigned int)(d.y & 255) << 16);
    bin[p2] = (unsigned int)s.z | ((unsigned int)(d.z & 255) << 16);
    bin[p3] = (unsigned int)s.w | ((unsigned int)(d.w & 255) << 16);
  } else {
    for (int e = base; e < E; ++e) {
      int p = atomicAdd(&gcurP[(dst[e] >> 8) * 16], 1);
      bin[p] = (unsigned int)src[e] | ((unsigned int)(dst[e] & 255) << 16);
    }
  }
}

// per-bucket counting sort: emits eidx (sorted by dst) + off for its dsts
__global__ __launch_bounds__(256) void bucket_sort(const unsigned int* __restrict__ bin,
                                                   const int* __restrict__ bbases,
                                                   unsigned short* __restrict__ eidx,
                                                   int* __restrict__ off,
                                                   int N, int NB) {
  const int b = blockIdx.x;
  const int bb = bbases[b], be = bbases[b + 1];
  const int d0 = b << 8;
  const int ndst = min(256, N - d0);
  __shared__ int hist[256];
  __shared__ int lofs[256];
  __shared__ int cnt2[256];
  const int tid = threadIdx.x;
  hist[tid] = 0;
  cnt2[tid] = 0;
  __syncthreads();
  for (int i = bb + tid; i < be; i += 256)
    atomicAdd(&hist[(bin[i] >> 16) & 255], 1);
  __syncthreads();
  if (tid < 64) {
    int l = tid;
    int v0 = hist[4 * l], v1 = hist[4 * l + 1], v2 = hist[4 * l + 2], v3 = hist[4 * l + 3];
    int s1 = v0 + v1, s2 = s1 + v2, t = s2 + v3;
    int x = t;
    #pragma unroll
    for (int d = 1; d < 64; d <<= 1) { int y = __shfl_up(x, d); if (l >= d) x += y; }
    int basex = x - t;
    lofs[4 * l] = basex;
    lofs[4 * l + 1] = basex + v0;
    lofs[4 * l + 2] = basex + s1;
    lofs[4 * l + 3] = basex + s2;
  }
  __syncthreads();
  if (tid < ndst) off[d0 + tid] = bb + lofs[tid];
  if (b == NB - 1 && tid == 0) off[N] = be;
  for (int i = bb + tid; i < be; i += 256) {
    unsigned int rec = bin[i];
    int ld = (rec >> 16) & 255;
    int p = bb + lofs[ld] + atomicAdd(&cnt2[ld], 1);
    eidx[p] = (unsigned short)(rec & 0xFFFF);
  }
}

// ===========================================================================
// Fallback CSR build (N > 65536): count + 3-phase scan + direct fill (int)
// ===========================================================================
__global__ void count_kernel(const int* __restrict__ dst, int* __restrict__ cnt, int E) {
  int base = (blockIdx.x * blockDim.x + threadIdx.x) * 4;
  if (base + 3 < E) {
    int4 d = *(const int4*)&dst[base];
    atomicAdd(&cnt[d.x], 1);
    atomicAdd(&cnt[d.y], 1);
    atomicAdd(&cnt[d.z], 1);
    atomicAdd(&cnt[d.w], 1);
  } else {
    for (int e = base; e < E; ++e) atomicAdd(&cnt[dst[e]], 1);
  }
}

__global__ __launch_bounds__(1024) void scan_local(const int* __restrict__ cnt,
                                                   int* __restrict__ off,
                                                   int* __restrict__ psum, int n) {
  __shared__ int wsum[16];
  const int tid = threadIdx.x, lane = tid & 63, wid = tid >> 6;
  int i = blockIdx.x * 1024 + tid;
  int v = (i < n) ? cnt[i] : 0;
  int x = v;
  #pragma unroll
  for (int d = 1; d < 64; d <<= 1) { int y = __shfl_up(x, d); if (lane >= d) x += y; }
  if (lane == 63) wsum[wid] = x;
  __syncthreads();
  if (wid == 0) {
    int ws = (lane < 16) ? wsum[lane] : 0;
    #pragma unroll
    for (int d = 1; d < 16; d <<= 1) { int y = __shfl_up(ws, d); if (lane >= d) ws += y; }
    if (lane < 16) wsum[lane] = ws;
  }
  __syncthreads();
  int excl = x - v + (wid ? wsum[wid - 1] : 0);
  if (i < n) off[i] = excl;
  if (tid == 1023) psum[blockIdx.x] = wsum[15];
}

__global__ __launch_bounds__(1024) void scan_carry(int* __restrict__ psum,
                                                   int* __restrict__ off,
                                                   int* __restrict__ cur, int nb, int n) {
  __shared__ int wsum[16];
  const int tid = threadIdx.x, lane = tid & 63, wid = tid >> 6;
  int v = (tid < nb) ? psum[tid] : 0;
  int x = v;
  #pragma unroll
  for (int d = 1; d < 64; d <<= 1) { int y = __shfl_up(x, d); if (lane >= d) x += y; }
  if (lane == 63) wsum[wid] = x;
  __syncthreads();
  if (wid == 0) {
    int ws = (lane < 16) ? wsum[lane] : 0;
    #pragma unroll
    for (int d = 1; d < 16; d <<= 1) { int y = __shfl_up(ws, d); if (lane >= d) ws += y; }
    if (lane < 16) wsum[lane] = ws;
  }
  __syncthreads();
  int excl = x - v + (wid ? wsum[wid - 1] : 0);
  if (tid < nb) psum[tid] = excl;
  if (tid == 1023) { off[n] = wsum[15]; cur[n] = wsum[15]; }
}

__global__ __launch_bounds__(1024) void scan_add(int* __restrict__ off, int* __restrict__ cur,
                                                 const int* __restrict__ psum, int n) {
  int i = blockIdx.x * 1024 + threadIdx.x;
  if (i < n) {
    int t = off[i] + psum[blockIdx.x];
    off[i] = t;
    cur[i] = t;
  }
}

__global__ void fill_kernel(const int* __restrict__ src, const int* __restrict__ dst,
                            int* __restrict__ cur, int* __restrict__ eidx, int E) {
  int base = (blockIdx.x * blockDim.x + threadIdx.x) * 4;
  if (base + 3 < E) {
    int4 d = *(const int4*)&dst[base];
    int4 s = *(const int4*)&src[base];
    int p0 = atomicAdd(&cur[d.x], 1);
    int p1 = atomicAdd(&cur[d.y], 1);
    int p2 = atomicAdd(&cur[d.z], 1);
    int p3 = atomicAdd(&cur[d.w], 1);
    eidx[p0] = s.x; eidx[p1] = s.y; eidx[p2] = s.z; eidx[p3] = s.w;
  } else {
    for (int e = base; e < E; ++e) {
      int p = atomicAdd(&cur[dst[e]], 1);
      eidx[p] = src[e];
    }
  }
}

// ===========================================================================
// Pack P0[n] = [nf[n] | H[n]] as f16 [N,256]
// ===========================================================================
__global__ void pack_nfh(const float* __restrict__ nf, const float* __restrict__ H,
                         f16* __restrict__ P0, int N) {
  int gid = blockIdx.x * blockDim.x + threadIdx.x;
  int w = gid >> 6;
  if (w >= N) return;
  int lane = threadIdx.x & 63;
  const float* S = (lane < 32) ? nf : H;
  int c = (lane & 31) * 4;
  float4 u = *(const float4*)&S[(size_t)w * 128 + c];
  f16x4 o = {(f16)u.x, (f16)u.y, (f16)u.z, (f16)u.w};
  *(f16x4*)&P0[(size_t)w * 256 + (lane < 32 ? 0 : 128) + c] = o;
}

// ===========================================================================
// Weight pre-transpose: Wt[n][k] f16 from W[k][n] f32
// ===========================================================================
__global__ void wtrans_all(const float* __restrict__ Wm, const float* __restrict__ Wz,
                           const float* __restrict__ Wr, const float* __restrict__ Wh,
                           f16* __restrict__ WtM, f16* __restrict__ WtZR,
                           f16* __restrict__ WtH) {
  __shared__ float tile[32][33];
  const float* W;
  f16* O;
  int K;
  switch (blockIdx.z) {
    case 0: W = Wm; O = WtM; K = 128; break;
    case 1: W = Wz; O = WtZR; K = 256; break;
    case 2: W = Wr; O = WtZR + 128 * 256; K = 256; break;
    default: W = Wh; O = WtH; K = 256; break;
  }
  int bk = blockIdx.x * 32, bn = blockIdx.y * 32;
  if (bk >= K) return;
  int tx = threadIdx.x, ty = threadIdx.y;   // 32 x 8
  #pragma unroll
  for (int i = 0; i < 4; ++i)
    tile[ty + 8 * i][tx] = W[(size_t)(bk + ty + 8 * i) * 128 + bn + tx];
  __syncthreads();
  #pragma unroll
  for (int i = 0; i < 4; ++i)
    O[(size_t)(bn + ty + 8 * i) * K + bk + tx] = (f16)tile[tx][ty + 8 * i];
}

// ===========================================================================
// Gather v4: each 16/32-lane GROUP owns one node (4 or 2 nodes/wave).
// f16x8 (16B) per lane covers the whole row; 8-deep unroll -> 8KB in
// flight per wave.  f32 accumulate, f16 out.
// ===========================================================================
template <int COLS, typename IDX>
__global__ __launch_bounds__(256) void gather(const f16* __restrict__ P,
                                              const int* __restrict__ off,
                                              const IDX* __restrict__ eidx,
                                              f16* __restrict__ O, int N) {
  constexpr int NG = (COLS == 256) ? 2 : 4;   // node-groups per wave
  constexpr int GL = 64 / NG;                 // lanes per group
  constexpr int SH = (COLS == 256) ? 9 : 8;   // row bytes shift
  int gid = blockIdx.x * blockDim.x + threadIdx.x;
  int wave = gid >> 6;
  int lane = threadIdx.x & 63;
  int g = lane / GL, lg = lane % GL;
  int node = wave * NG + g;
  if (node >= N) return;
  const int beg = off[node], end = off[node + 1];
  const char* base = (const char*)P + lg * 16;
  float a0 = 0.f, a1 = 0.f, a2 = 0.f, a3 = 0.f;
  float a4 = 0.f, a5 = 0.f, a6 = 0.f, a7 = 0.f;
  int j = beg;
  for (; j + 8 <= end; j += 8) {
    f16x8 v[8];
    #pragma unroll
    for (int u = 0; u < 8; ++u)
      v[u] = *(const f16x8*)(base + (((int)eidx[j + u]) << SH));
    #pragma unroll
    for (int u = 0; u < 8; ++u) {
      a0 += (float)v[u][0]; a1 += (float)v[u][1];
      a2 += (float)v[u][2]; a3 += (float)v[u][3];
      a4 += (float)v[u][4]; a5 += (float)v[u][5];
      a6 += (float)v[u][6]; a7 += (float)v[u][7];
    }
  }
  for (; j < end; ++j) {
    f16x8 v = *(const f16x8*)(base + (((int)eidx[j]) << SH));
    a0 += (float)v[0]; a1 += (float)v[1]; a2 += (float)v[2]; a3 += (float)v[3];
    a4 += (float)v[4]; a5 += (float)v[5]; a6 += (float)v[6]; a7 += (float)v[7];
  }
  f16x8 o = {(f16)a0, (f16)a1, (f16)a2, (f16)a3, (f16)a4, (f16)a5, (f16)a6, (f16)a7};
  *(f16x8*)&O[(size_t)node * COLS + lg * 8] = o;
}

// ===========================================================================
// MFMA GEMM v3: 64x128 tile, 4 waves (each 16 rows x 128 cols), BK=64,
// double-buffered LDS (48KB), counted vmcnt (never 0 mid-loop), raw
// s_barrier.  XOR-granule swizzle, global_load_lds staging.  f16 in, f32 acc.
// EPI 0: O0 = relu(acc+b0)
// EPI 1: coff==0: O0 = sig(acc+b0);  coff!=0: O1 = sig(acc+b1)*H
// EPI 2: Ofp = Zh*H + (1-Zh)*tanh(acc+b0)
// ===========================================================================
template <int TERMS, int EPI>
__global__ __launch_bounds__(256) void gemm_mfma(
    const f16* __restrict__ A0, int lda0, const f16* __restrict__ A1, int lda1,
    const f16* __restrict__ Wt,
    const float* __restrict__ b0, const float* __restrict__ b1,
    const float* __restrict__ H, const f16* __restrict__ Zh,
    f16* __restrict__ O0, f16* __restrict__ O1, float* __restrict__ Ofp, int N) {
  constexpr int KTOT = TERMS * 128;
  constexpr int T = KTOT / 64;
  __shared__ __align__(16) f16 As[2][64][64];
  __shared__ __align__(16) f16 Bs[2][128][64];
  const int tid = threadIdx.x;
  const int l = tid & 63;
  const int wv = __builtin_amdgcn_readfirstlane(tid >> 6);
  const int fr = l & 15;
  const int q = l >> 4;
  const int brow = blockIdx.x * 64;
  const int coff = blockIdx.y * 128;
  const int rowA = wv * 16 + fr;
  const int sl8 = l >> 3, sg = l & 7;

  f32x4_t acc[8];
  #pragma unroll
  for (int n = 0; n < 8; ++n) acc[n] = (f32x4_t)0.0f;

  auto stage = [&](int t, int buf) {
    const bool sel1 = (TERMS == 2) && (t >= 2);
    const f16* __restrict__ A = sel1 ? A1 : A0;
    const int lda = sel1 ? lda1 : lda0;
    const int klocal = (t & 1) * 64;
    const int kk = t * 64;
    f16* Asf = &As[buf][0][0];
    f16* Bsf = &Bs[buf][0][0];
    #pragma unroll
    for (int c = 0; c < 2; ++c) {
      int chunk = wv + c * 4;
      int row = chunk * 8 + sl8;
      int gs = sg ^ (row & 7);
      int grow = brow + row;
      if (grow > N - 1) grow = N - 1;
      GLDS16(A + (size_t)grow * lda + klocal + gs * 8, Asf + chunk * 512);
    }
    #pragma unroll
    for (int c = 0; c < 4; ++c) {
      int chunk = wv + c * 4;
      int col = chunk * 8 + sl8;
      int gs = sg ^ (col & 7);
      GLDS16(Wt + (size_t)(coff + col) * KTOT + kk + gs * 8, Bsf + chunk * 512);
    }
  };

  stage(0, 0);
  #pragma unroll
  for (int t = 0; t < T; ++t) {
    if (t + 1 < T) {
      stage(t + 1, (t + 1) & 1);
      asm volatile("s_waitcnt vmcnt(6)" ::: "memory");   // tile t landed
    } else {
      asm volatile("s_waitcnt vmcnt(0)" ::: "memory");
    }
    __builtin_amdgcn_s_barrier();
    const int buf = t & 1;
    #pragma unroll
    for (int ks = 0; ks < 2; ++ks) {
      f16x8 a = *(const f16x8*)&As[buf][rowA][((ks * 4 + q) ^ (rowA & 7)) * 8];
      f16x8 bfr[8];
      #pragma unroll
      for (int n = 0; n < 8; ++n) {
        int colB = n * 16 + fr;
        bfr[n] = *(const f16x8*)&Bs[buf][colB][((ks * 4 + q) ^ (colB & 7)) * 8];
      }
      #pragma unroll
      for (int n = 0; n < 8; ++n)
        acc[n] = __builtin_amdgcn_mfma_f32_16x16x32_f16(a, bfr[n], acc[n], 0, 0, 0);
    }
    asm volatile("s_waitcnt lgkmcnt(0)" ::: "memory");   // reads done before overwrite
    __builtin_amdgcn_s_barrier();
  }

  const int row0 = brow + wv * 16 + q * 4;
  #pragma unroll
  for (int n = 0; n < 8; ++n) {
    int colL = n * 16 + fr;
    if (EPI == 0) {
      float bias = b0[colL];
      #pragma unroll
      for (int r = 0; r < 4; ++r) {
        int row = row0 + r;
        if (row < N)
          O0[(size_t)row * 128 + colL] = (f16)fmaxf(acc[n][r] + bias, 0.f);
      }
    } else if (EPI == 1) {
      if (coff == 0) {
        float bias = b0[colL];
        #pragma unroll
        for (int r = 0; r < 4; ++r) {
          int row = row0 + r;
          if (row < N)
            O0[(size_t)row * 128 + colL] = (f16)sigmoidf(acc[n][r] + bias);
        }
      } else {
        float bias = b1[colL];
        #pragma unroll
        for (int r = 0; r < 4; ++r) {
          int row = row0 + r;
          if (row < N) {
            float g = sigmoidf(acc[n][r] + bias) * H[(size_t)row * 128 + colL];
            O1[(size_t)row * 128 + colL] = (f16)g;
          }
        }
      }
    } else {
      float bias = b0[colL];
      #pragma unroll
      for (int r = 0; r < 4; ++r) {
        int row = row0 + r;
        if (row < N) {
          size_t p = (size_t)row * 128 + colL;
          float ht = tanhf(acc[n][r] + bias);
          float z = (float)Zh[p];
          float h = H[p];
          Ofp[p] = z * h + (1.0f - z) * ht;
        }
      }
    }
  }
}

// ===========================================================================

extern "C" void kernel_launch(void* const* d_in, const int* in_sizes, int n_in,
                              void* d_out, int out_size, void* d_ws, size_t ws_size,
                              hipStream_t stream) {
  const float* nf = (const float*)d_in[0];
  const float* H  = (const float*)d_in[1];
  const int*   ei = (const int*)d_in[2];
  const float* Wm = (const float*)d_in[3];
  const float* bm = (const float*)d_in[4];
  const float* Wz = (const float*)d_in[5];
  const float* bz = (const float*)d_in[6];
  const float* Wr = (const float*)d_in[7];
  const float* br = (const float*)d_in[8];
  const float* Wh = (const float*)d_in[9];
  const float* bh = (const float*)d_in[10];
  float* out = (float*)d_out;

  const int N = in_sizes[0] / 128;
  const int E = in_sizes[2] / 2;
  const int* src = ei;
  const int* dst = ei + E;

  char* ws = (char*)d_ws;
  size_t o = 0;
  auto alloc = [&](size_t bytes) {
    char* p = ws + o;
    o = (o + bytes + 511) & ~(size_t)511;
    return p;
  };
  const int NB = (N + 255) >> 8;             // radix buckets
  const int nbch = (N + 1023) / 1024;        // fallback scan chunks
  int* bcntP  = (int*)alloc((size_t)NB * 16 * 4);
  int* gcurP  = (int*)alloc((size_t)NB * 16 * 4);
  int* bbases = (int*)alloc((size_t)(NB + 1) * 4);
  unsigned int* bin = (unsigned int*)alloc((size_t)E * 4);
  int* off    = (int*)alloc((size_t)(N + 1) * 4);
  int* cur    = (int*)alloc((size_t)(N + 1) * 4);   // fallback
  int* cnt    = (int*)alloc((size_t)N * 4);          // fallback
  int* psum   = (int*)alloc((size_t)nbch * 4);       // fallback
  void* eidx  = (void*)alloc((size_t)E * 4);
  f16* WtM    = (f16*)alloc((size_t)128 * 128 * 2);
  f16* WtZR   = (f16*)alloc((size_t)256 * 256 * 2);
  f16* WtH    = (f16*)alloc((size_t)128 * 256 * 2);
  f16* P0     = (f16*)alloc((size_t)N * 256 * 2);   // [nf|H] packed
  f16* X      = (f16*)alloc((size_t)N * 128 * 2);
  f16* AX     = (f16*)alloc((size_t)N * 128 * 2);
  f16* G      = (f16*)alloc((size_t)N * 128 * 2);
  f16* AP0    = (f16*)d_out;                        // dead before final write
  f16* Zh     = X;                                  // X dead after gather(X)
  f16* AG     = P0;                                 // P0 dead after gather(P0)

  const bool small = (N <= 65536);
  const int qblk = ((E + 3) / 4 + 255) / 256;

  // --- CSR build ---
  if (small) {
    zero_ints<<<(NB * 16 + 255) / 256, 256, 0, stream>>>(bcntP, NB * 16);
    bucket_hist<<<qblk, 256, 0, stream>>>(dst, bcntP, E, NB);
    bucket_scan<<<1, 256, 0, stream>>>(bcntP, bbases, gcurP, NB);
    partition_k<<<qblk, 256, 0, stream>>>(src, dst, gcurP, bin, E);
    bucket_sort<<<NB, 256, 0, stream>>>(bin, bbases, (unsigned short*)eidx, off, N, NB);
  } else {
    zero_ints<<<(N + 255) / 256, 256, 0, stream>>>(cnt, N);
    count_kernel<<<qblk, 256, 0, stream>>>(dst, cnt, E);
    scan_local<<<nbch, 1024, 0, stream>>>(cnt, off, psum, N);
    scan_carry<<<1, 1024, 0, stream>>>(psum, off, cur, nbch, N);
    scan_add<<<nbch, 1024, 0, stream>>>(off, cur, psum, N);
    fill_kernel<<<qblk, 256, 0, stream>>>(src, dst, cur, (int*)eidx, E);
  }

  // --- weight transpose + input pack ---
  wtrans_all<<<dim3(8, 4, 4), dim3(32, 8), 0, stream>>>(Wm, Wz, Wr, Wh, WtM, WtZR, WtH);
  const int pblk = (N * 64 + 255) / 256;
  pack_nfh<<<pblk, 256, 0, stream>>>(nf, H, P0, N);

  const int mblk = (N + 63) / 64;
  const int g256 = (N + 7) / 8;     // 2 nodes/wave, 4 waves/block
  const int g128 = (N + 15) / 16;   // 4 nodes/wave

  // --- AP0 = Agg([nf|H]) ---
  if (small)
    gather<256, unsigned short><<<g256, 256, 0, stream>>>(P0, off, (const unsigned short*)eidx, AP0, N);
  else
    gather<256, int><<<g256, 256, 0, stream>>>(P0, off, (const int*)eidx, AP0, N);

  // --- X = relu(Anf @ Wm + bm) ---
  gemm_mfma<1, 0><<<dim3(mblk, 1), 256, 0, stream>>>(
      AP0, 256, nullptr, 0, WtM, bm, nullptr, nullptr, nullptr, X, nullptr, nullptr, N);

  // --- AX = Agg(X) ---
  if (small)
    gather<128, unsigned short><<<g128, 256, 0, stream>>>(X, off, (const unsigned short*)eidx, AX, N);
  else
    gather<128, int><<<g128, 256, 0, stream>>>(X, off, (const int*)eidx, AX, N);

  // --- Z = sig([AX,AH]@Wz+bz), G = sig([AX,AH]@Wr+br)*H ---
  gemm_mfma<2, 1><<<dim3(mblk, 2), 256, 0, stream>>>(
      AX, 128, AP0 + 128, 256, WtZR, bz, br, H, nullptr, Zh, G, nullptr, N);

  // --- AG = Agg(G) ---
  if (small)
    gather<128, unsigned short><<<g128, 256, 0, stream>>>(G, off, (const unsigned short*)eidx, AG, N);
  else
    gather<128, int><<<g128, 256, 0, stream>>>(G, off, (const int*)eidx, AG, N);

  // --- out = Zh*H + (1-Zh)*tanh([AX,AG]@Wh + bh) ---
  gemm_mfma<2, 2><<<dim3(mblk, 1), 256, 0, stream>>>(
      AX, 128, AG, 128, WtH, bh, nullptr, H, Zh, nullptr, nullptr, out, N);
}

// Round 7
// 281.822 us; speedup vs baseline: 1.2570x; 1.2570x over previous
//
#include <hip/hip_runtime.h>
#include <hip/hip_fp16.h>
#include <math.h>

typedef _Float16 f16;
typedef f16 f16x2 __attribute__((ext_vector_type(2)));
typedef f16 f16x4 __attribute__((ext_vector_type(4)));
typedef f16 f16x8 __attribute__((ext_vector_type(8)));
typedef float f32x4_t __attribute__((ext_vector_type(4)));

__device__ __forceinline__ float sigmoidf(float x) {
  return 1.0f / (1.0f + __expf(-x));
}

// direct-to-LDS 16B copy: LDS dest = wave-uniform base + lane*16
#define GLDS16(gp, lp)                                                     \
  __builtin_amdgcn_global_load_lds(                                        \
      (const __attribute__((address_space(1))) void*)(gp),                 \
      (__attribute__((address_space(3))) void*)(lp), 16, 0, 0)

__global__ void zero_ints(int* __restrict__ p, int n) {
  int i = blockIdx.x * blockDim.x + threadIdx.x;
  if (i < n) p[i] = 0;
}

// ===========================================================================
// CSR build v3 (N <= 65536): 256-node radix buckets, block-local staging.
//   bucket b = dst >> 8 ; bcntP/gcurP padded stride 16 ints (1 line/bucket)
// ===========================================================================
__global__ void bucket_hist(const int* __restrict__ dst, int* __restrict__ bcntP,
                            int E, int NB) {
  __shared__ int h[256];
  for (int i = threadIdx.x; i < NB; i += 256) h[i] = 0;
  __syncthreads();
  int base = (blockIdx.x * 256 + threadIdx.x) * 4;
  if (base + 3 < E) {
    int4 d = *(const int4*)&dst[base];
    atomicAdd(&h[d.x >> 8], 1);
    atomicAdd(&h[d.y >> 8], 1);
    atomicAdd(&h[d.z >> 8], 1);
    atomicAdd(&h[d.w >> 8], 1);
  } else {
    for (int e = base; e < E; ++e) atomicAdd(&h[dst[e] >> 8], 1);
  }
  __syncthreads();
  for (int i = threadIdx.x; i < NB; i += 256)
    if (h[i]) atomicAdd(&bcntP[i * 16], h[i]);
}

// single block, 256 threads: exclusive scan of NB bucket counts
__global__ __launch_bounds__(256) void bucket_scan(const int* __restrict__ bcntP,
                                                   int* __restrict__ bbases,
                                                   int* __restrict__ gcurP, int NB) {
  __shared__ int wsum[4];
  const int tid = threadIdx.x, lane = tid & 63, wid = tid >> 6;
  int v = (tid < NB) ? bcntP[tid * 16] : 0;
  int x = v;
  #pragma unroll
  for (int d = 1; d < 64; d <<= 1) { int y = __shfl_up(x, d); if (lane >= d) x += y; }
  if (lane == 63) wsum[wid] = x;
  __syncthreads();
  if (wid == 0 && lane < 4) {
    int ws = wsum[lane];
    #pragma unroll
    for (int d = 1; d < 4; d <<= 1) { int y = __shfl_up(ws, d); if (lane >= d) ws += y; }
    wsum[lane] = ws;
  }
  __syncthreads();
  int excl = x - v + (wid ? wsum[wid - 1] : 0);
  if (tid < NB) { bbases[tid] = excl; gcurP[tid * 16] = excl; }
  if (tid == NB - 1) bbases[NB] = excl + v;
}

// partition v2: block-local staging.  4096 edges/block kept in registers,
// LDS histogram -> local scan -> ONE global reserve per (block,bucket) ->
// LDS counting-scatter -> bucket-ordered coalesced flush to bin.
__global__ __launch_bounds__(256) void partition_v2(const int* __restrict__ src,
                                                    const int* __restrict__ dst,
                                                    int* __restrict__ gcurP,
                                                    unsigned int* __restrict__ bin,
                                                    int E, int NB) {
  __shared__ int bhist[256];
  __shared__ int bofs[257];
  __shared__ int gbase[256];
  __shared__ unsigned int recs[4096];
  const int tid = threadIdx.x;
  const int base = blockIdx.x * 4096;
  bhist[tid] = 0;
  __syncthreads();
  unsigned int rec[16];
  int bk[16];
  #pragma unroll
  for (int k = 0; k < 16; ++k) {
    int e = base + tid + k * 256;
    if (e < E) {
      int d = dst[e];
      rec[k] = (unsigned int)(src[e] & 0xFFFF) | ((unsigned int)(d & 255) << 16);
      bk[k] = d >> 8;
      atomicAdd(&bhist[bk[k]], 1);
    } else {
      bk[k] = -1;
    }
  }
  __syncthreads();
  // exclusive scan of 256 bucket counts -> bofs[0..256]
  if (tid < 64) {
    int l = tid;
    int v0 = bhist[4 * l], v1 = bhist[4 * l + 1];
    int v2 = bhist[4 * l + 2], v3 = bhist[4 * l + 3];
    int s1 = v0 + v1, s2 = s1 + v2, t = s2 + v3;
    int x = t;
    #pragma unroll
    for (int d = 1; d < 64; d <<= 1) { int y = __shfl_up(x, d); if (l >= d) x += y; }
    int basex = x - t;
    bofs[4 * l] = basex;
    bofs[4 * l + 1] = basex + v0;
    bofs[4 * l + 2] = basex + s1;
    bofs[4 * l + 3] = basex + s2;
    if (l == 63) bofs[256] = x;
  }
  __syncthreads();
  // one global reserve per non-empty bucket; then reuse bhist as local cursor
  if (tid < NB && bhist[tid] > 0)
    gbase[tid] = atomicAdd(&gcurP[tid * 16], bhist[tid]);
  bhist[tid] = bofs[tid];
  __syncthreads();
  #pragma unroll
  for (int k = 0; k < 16; ++k) {
    if (bk[k] >= 0) {
      int p = atomicAdd(&bhist[bk[k]], 1);
      recs[p] = rec[k];
    }
  }
  __syncthreads();
  const int total = bofs[256];
  for (int i = tid; i < total; i += 256) {
    int lo = 0, hi = 256;
    #pragma unroll
    for (int s = 0; s < 8; ++s) {
      int mid = (lo + hi) >> 1;
      if (bofs[mid] <= i) lo = mid; else hi = mid;
    }
    bin[gbase[lo] + (i - bofs[lo])] = recs[i];
  }
}

// per-bucket counting sort: LDS-sorted, coalesced u16 flush
__global__ __launch_bounds__(256) void bucket_sort(const unsigned int* __restrict__ bin,
                                                   const int* __restrict__ bbases,
                                                   unsigned short* __restrict__ eidx,
                                                   int* __restrict__ off,
                                                   int N, int NB) {
  const int b = blockIdx.x;
  const int bb = bbases[b], be = bbases[b + 1];
  const int cntb = be - bb;
  const int d0 = b << 8;
  const int ndst = min(256, N - d0);
  __shared__ int hist[256];
  __shared__ int lofs[256];
  __shared__ int cnt2[256];
  __shared__ unsigned short srt[8192];
  const int tid = threadIdx.x;
  hist[tid] = 0;
  cnt2[tid] = 0;
  __syncthreads();
  for (int i = bb + tid; i < be; i += 256)
    atomicAdd(&hist[(bin[i] >> 16) & 255], 1);
  __syncthreads();
  if (tid < 64) {
    int l = tid;
    int v0 = hist[4 * l], v1 = hist[4 * l + 1], v2 = hist[4 * l + 2], v3 = hist[4 * l + 3];
    int s1 = v0 + v1, s2 = s1 + v2, t = s2 + v3;
    int x = t;
    #pragma unroll
    for (int d = 1; d < 64; d <<= 1) { int y = __shfl_up(x, d); if (l >= d) x += y; }
    int basex = x - t;
    lofs[4 * l] = basex;
    lofs[4 * l + 1] = basex + v0;
    lofs[4 * l + 2] = basex + s1;
    lofs[4 * l + 3] = basex + s2;
  }
  __syncthreads();
  if (tid < ndst) off[d0 + tid] = bb + lofs[tid];
  if (b == NB - 1 && tid == 0) off[N] = be;
  if (cntb <= 8192) {
    for (int i = bb + tid; i < be; i += 256) {
      unsigned int r = bin[i];
      int ld = (r >> 16) & 255;
      int p = lofs[ld] + atomicAdd(&cnt2[ld], 1);
      srt[p] = (unsigned short)(r & 0xFFFF);
    }
    __syncthreads();
    for (int i = tid; i < cntb; i += 256) eidx[bb + i] = srt[i];
  } else {
    for (int i = bb + tid; i < be; i += 256) {
      unsigned int r = bin[i];
      int ld = (r >> 16) & 255;
      int p = bb + lofs[ld] + atomicAdd(&cnt2[ld], 1);
      eidx[p] = (unsigned short)(r & 0xFFFF);
    }
  }
}

// ===========================================================================
// Fallback CSR build (N > 65536): count + 3-phase scan + direct fill (int)
// ===========================================================================
__global__ void count_kernel(const int* __restrict__ dst, int* __restrict__ cnt, int E) {
  int base = (blockIdx.x * blockDim.x + threadIdx.x) * 4;
  if (base + 3 < E) {
    int4 d = *(const int4*)&dst[base];
    atomicAdd(&cnt[d.x], 1);
    atomicAdd(&cnt[d.y], 1);
    atomicAdd(&cnt[d.z], 1);
    atomicAdd(&cnt[d.w], 1);
  } else {
    for (int e = base; e < E; ++e) atomicAdd(&cnt[dst[e]], 1);
  }
}

__global__ __launch_bounds__(1024) void scan_local(const int* __restrict__ cnt,
                                                   int* __restrict__ off,
                                                   int* __restrict__ psum, int n) {
  __shared__ int wsum[16];
  const int tid = threadIdx.x, lane = tid & 63, wid = tid >> 6;
  int i = blockIdx.x * 1024 + tid;
  int v = (i < n) ? cnt[i] : 0;
  int x = v;
  #pragma unroll
  for (int d = 1; d < 64; d <<= 1) { int y = __shfl_up(x, d); if (lane >= d) x += y; }
  if (lane == 63) wsum[wid] = x;
  __syncthreads();
  if (wid == 0) {
    int ws = (lane < 16) ? wsum[lane] : 0;
    #pragma unroll
    for (int d = 1; d < 16; d <<= 1) { int y = __shfl_up(ws, d); if (lane >= d) ws += y; }
    if (lane < 16) wsum[lane] = ws;
  }
  __syncthreads();
  int excl = x - v + (wid ? wsum[wid - 1] : 0);
  if (i < n) off[i] = excl;
  if (tid == 1023) psum[blockIdx.x] = wsum[15];
}

__global__ __launch_bounds__(1024) void scan_carry(int* __restrict__ psum,
                                                   int* __restrict__ off,
                                                   int* __restrict__ cur, int nb, int n) {
  __shared__ int wsum[16];
  const int tid = threadIdx.x, lane = tid & 63, wid = tid >> 6;
  int v = (tid < nb) ? psum[tid] : 0;
  int x = v;
  #pragma unroll
  for (int d = 1; d < 64; d <<= 1) { int y = __shfl_up(x, d); if (lane >= d) x += y; }
  if (lane == 63) wsum[wid] = x;
  __syncthreads();
  if (wid == 0) {
    int ws = (lane < 16) ? wsum[lane] : 0;
    #pragma unroll
    for (int d = 1; d < 16; d <<= 1) { int y = __shfl_up(ws, d); if (lane >= d) ws += y; }
    if (lane < 16) wsum[lane] = ws;
  }
  __syncthreads();
  int excl = x - v + (wid ? wsum[wid - 1] : 0);
  if (tid < nb) psum[tid] = excl;
  if (tid == 1023) { off[n] = wsum[15]; cur[n] = wsum[15]; }
}

__global__ __launch_bounds__(1024) void scan_add(int* __restrict__ off, int* __restrict__ cur,
                                                 const int* __restrict__ psum, int n) {
  int i = blockIdx.x * 1024 + threadIdx.x;
  if (i < n) {
    int t = off[i] + psum[blockIdx.x];
    off[i] = t;
    cur[i] = t;
  }
}

__global__ void fill_kernel(const int* __restrict__ src, const int* __restrict__ dst,
                            int* __restrict__ cur, int* __restrict__ eidx, int E) {
  int base = (blockIdx.x * blockDim.x + threadIdx.x) * 4;
  if (base + 3 < E) {
    int4 d = *(const int4*)&dst[base];
    int4 s = *(const int4*)&src[base];
    int p0 = atomicAdd(&cur[d.x], 1);
    int p1 = atomicAdd(&cur[d.y], 1);
    int p2 = atomicAdd(&cur[d.z], 1);
    int p3 = atomicAdd(&cur[d.w], 1);
    eidx[p0] = s.x; eidx[p1] = s.y; eidx[p2] = s.z; eidx[p3] = s.w;
  } else {
    for (int e = base; e < E; ++e) {
      int p = atomicAdd(&cur[dst[e]], 1);
      eidx[p] = src[e];
    }
  }
}

// ===========================================================================
// Pack P0[n] = [nf[n] | H[n]] as f16 [N,256]
// ===========================================================================
__global__ void pack_nfh(const float* __restrict__ nf, const float* __restrict__ H,
                         f16* __restrict__ P0, int N) {
  int gid = blockIdx.x * blockDim.x + threadIdx.x;
  int w = gid >> 6;
  if (w >= N) return;
  int lane = threadIdx.x & 63;
  const float* S = (lane < 32) ? nf : H;
  int c = (lane & 31) * 4;
  float4 u = *(const float4*)&S[(size_t)w * 128 + c];
  f16x4 o = {(f16)u.x, (f16)u.y, (f16)u.z, (f16)u.w};
  *(f16x4*)&P0[(size_t)w * 256 + (lane < 32 ? 0 : 128) + c] = o;
}

// ===========================================================================
// Weight pre-transpose: Wt[n][k] f16 from W[k][n] f32
// ===========================================================================
__global__ void wtrans_all(const float* __restrict__ Wm, const float* __restrict__ Wz,
                           const float* __restrict__ Wr, const float* __restrict__ Wh,
                           f16* __restrict__ WtM, f16* __restrict__ WtZR,
                           f16* __restrict__ WtH) {
  __shared__ float tile[32][33];
  const float* W;
  f16* O;
  int K;
  switch (blockIdx.z) {
    case 0: W = Wm; O = WtM; K = 128; break;
    case 1: W = Wz; O = WtZR; K = 256; break;
    case 2: W = Wr; O = WtZR + 128 * 256; K = 256; break;
    default: W = Wh; O = WtH; K = 256; break;
  }
  int bk = blockIdx.x * 32, bn = blockIdx.y * 32;
  if (bk >= K) return;
  int tx = threadIdx.x, ty = threadIdx.y;   // 32 x 8
  #pragma unroll
  for (int i = 0; i < 4; ++i)
    tile[ty + 8 * i][tx] = W[(size_t)(bk + ty + 8 * i) * 128 + bn + tx];
  __syncthreads();
  #pragma unroll
  for (int i = 0; i < 4; ++i)
    O[(size_t)(bn + ty + 8 * i) * K + bk + tx] = (f16)tile[tx][ty + 8 * i];
}

// ===========================================================================
// Gather v4: each 16/32-lane GROUP owns one node (4 or 2 nodes/wave).
// f16x8 (16B) per lane covers the whole row; 8-deep unroll.
// ===========================================================================
template <int COLS, typename IDX>
__global__ __launch_bounds__(256) void gather(const f16* __restrict__ P,
                                              const int* __restrict__ off,
                                              const IDX* __restrict__ eidx,
                                              f16* __restrict__ O, int N) {
  constexpr int NG = (COLS == 256) ? 2 : 4;   // node-groups per wave
  constexpr int GL = 64 / NG;                 // lanes per group
  constexpr int SH = (COLS == 256) ? 9 : 8;   // row bytes shift
  int gid = blockIdx.x * blockDim.x + threadIdx.x;
  int wave = gid >> 6;
  int lane = threadIdx.x & 63;
  int g = lane / GL, lg = lane % GL;
  int node = wave * NG + g;
  if (node >= N) return;
  const int beg = off[node], end = off[node + 1];
  const char* base = (const char*)P + lg * 16;
  float a0 = 0.f, a1 = 0.f, a2 = 0.f, a3 = 0.f;
  float a4 = 0.f, a5 = 0.f, a6 = 0.f, a7 = 0.f;
  int j = beg;
  for (; j + 8 <= end; j += 8) {
    f16x8 v[8];
    #pragma unroll
    for (int u = 0; u < 8; ++u)
      v[u] = *(const f16x8*)(base + (((int)eidx[j + u]) << SH));
    #pragma unroll
    for (int u = 0; u < 8; ++u) {
      a0 += (float)v[u][0]; a1 += (float)v[u][1];
      a2 += (float)v[u][2]; a3 += (float)v[u][3];
      a4 += (float)v[u][4]; a5 += (float)v[u][5];
      a6 += (float)v[u][6]; a7 += (float)v[u][7];
    }
  }
  for (; j < end; ++j) {
    f16x8 v = *(const f16x8*)(base + (((int)eidx[j]) << SH));
    a0 += (float)v[0]; a1 += (float)v[1]; a2 += (float)v[2]; a3 += (float)v[3];
    a4 += (float)v[4]; a5 += (float)v[5]; a6 += (float)v[6]; a7 += (float)v[7];
  }
  f16x8 o = {(f16)a0, (f16)a1, (f16)a2, (f16)a3, (f16)a4, (f16)a5, (f16)a6, (f16)a7};
  *(f16x8*)&O[(size_t)node * COLS + lg * 8] = o;
}

// ===========================================================================
// MFMA GEMM v3: 64x128 tile, 4 waves, BK=64, double-buffered LDS, counted
// vmcnt, raw s_barrier, XOR-granule swizzle, global_load_lds staging.
// EPI 0: O0 = relu(acc+b0)
// EPI 1: coff==0: O0 = sig(acc+b0);  coff!=0: O1 = sig(acc+b1)*H
// EPI 2: Ofp = Zh*H + (1-Zh)*tanh(acc+b0)
// ===========================================================================
template <int TERMS, int EPI>
__global__ __launch_bounds__(256) void gemm_mfma(
    const f16* __restrict__ A0, int lda0, const f16* __restrict__ A1, int lda1,
    const f16* __restrict__ Wt,
    const float* __restrict__ b0, const float* __restrict__ b1,
    const float* __restrict__ H, const f16* __restrict__ Zh,
    f16* __restrict__ O0, f16* __restrict__ O1, float* __restrict__ Ofp, int N) {
  constexpr int KTOT = TERMS * 128;
  constexpr int T = KTOT / 64;
  __shared__ __align__(16) f16 As[2][64][64];
  __shared__ __align__(16) f16 Bs[2][128][64];
  const int tid = threadIdx.x;
  const int l = tid & 63;
  const int wv = __builtin_amdgcn_readfirstlane(tid >> 6);
  const int fr = l & 15;
  const int q = l >> 4;
  const int brow = blockIdx.x * 64;
  const int coff = blockIdx.y * 128;
  const int rowA = wv * 16 + fr;
  const int sl8 = l >> 3, sg = l & 7;

  f32x4_t acc[8];
  #pragma unroll
  for (int n = 0; n < 8; ++n) acc[n] = (f32x4_t)0.0f;

  auto stage = [&](int t, int buf) {
    const bool sel1 = (TERMS == 2) && (t >= 2);
    const f16* __restrict__ A = sel1 ? A1 : A0;
    const int lda = sel1 ? lda1 : lda0;
    const int klocal = (t & 1) * 64;
    const int kk = t * 64;
    f16* Asf = &As[buf][0][0];
    f16* Bsf = &Bs[buf][0][0];
    #pragma unroll
    for (int c = 0; c < 2; ++c) {
      int chunk = wv + c * 4;
      int row = chunk * 8 + sl8;
      int gs = sg ^ (row & 7);
      int grow = brow + row;
      if (grow > N - 1) grow = N - 1;
      GLDS16(A + (size_t)grow * lda + klocal + gs * 8, Asf + chunk * 512);
    }
    #pragma unroll
    for (int c = 0; c < 4; ++c) {
      int chunk = wv + c * 4;
      int col = chunk * 8 + sl8;
      int gs = sg ^ (col & 7);
      GLDS16(Wt + (size_t)(coff + col) * KTOT + kk + gs * 8, Bsf + chunk * 512);
    }
  };

  stage(0, 0);
  #pragma unroll
  for (int t = 0; t < T; ++t) {
    if (t + 1 < T) {
      stage(t + 1, (t + 1) & 1);
      asm volatile("s_waitcnt vmcnt(6)" ::: "memory");   // tile t landed
    } else {
      asm volatile("s_waitcnt vmcnt(0)" ::: "memory");
    }
    __builtin_amdgcn_s_barrier();
    const int buf = t & 1;
    #pragma unroll
    for (int ks = 0; ks < 2; ++ks) {
      f16x8 a = *(const f16x8*)&As[buf][rowA][((ks * 4 + q) ^ (rowA & 7)) * 8];
      f16x8 bfr[8];
      #pragma unroll
      for (int n = 0; n < 8; ++n) {
        int colB = n * 16 + fr;
        bfr[n] = *(const f16x8*)&Bs[buf][colB][((ks * 4 + q) ^ (colB & 7)) * 8];
      }
      #pragma unroll
      for (int n = 0; n < 8; ++n)
        acc[n] = __builtin_amdgcn_mfma_f32_16x16x32_f16(a, bfr[n], acc[n], 0, 0, 0);
    }
    asm volatile("s_waitcnt lgkmcnt(0)" ::: "memory");   // reads done before overwrite
    __builtin_amdgcn_s_barrier();
  }

  const int row0 = brow + wv * 16 + q * 4;
  #pragma unroll
  for (int n = 0; n < 8; ++n) {
    int colL = n * 16 + fr;
    if (EPI == 0) {
      float bias = b0[colL];
      #pragma unroll
      for (int r = 0; r < 4; ++r) {
        int row = row0 + r;
        if (row < N)
          O0[(size_t)row * 128 + colL] = (f16)fmaxf(acc[n][r] + bias, 0.f);
      }
    } else if (EPI == 1) {
      if (coff == 0) {
        float bias = b0[colL];
        #pragma unroll
        for (int r = 0; r < 4; ++r) {
          int row = row0 + r;
          if (row < N)
            O0[(size_t)row * 128 + colL] = (f16)sigmoidf(acc[n][r] + bias);
        }
      } else {
        float bias = b1[colL];
        #pragma unroll
        for (int r = 0; r < 4; ++r) {
          int row = row0 + r;
          if (row < N) {
            float g = sigmoidf(acc[n][r] + bias) * H[(size_t)row * 128 + colL];
            O1[(size_t)row * 128 + colL] = (f16)g;
          }
        }
      }
    } else {
      float bias = b0[colL];
      #pragma unroll
      for (int r = 0; r < 4; ++r) {
        int row = row0 + r;
        if (row < N) {
          size_t p = (size_t)row * 128 + colL;
          float ht = tanhf(acc[n][r] + bias);
          float z = (float)Zh[p];
          float h = H[p];
          Ofp[p] = z * h + (1.0f - z) * ht;
        }
      }
    }
  }
}

// ===========================================================================

extern "C" void kernel_launch(void* const* d_in, const int* in_sizes, int n_in,
                              void* d_out, int out_size, void* d_ws, size_t ws_size,
                              hipStream_t stream) {
  const float* nf = (const float*)d_in[0];
  const float* H  = (const float*)d_in[1];
  const int*   ei = (const int*)d_in[2];
  const float* Wm = (const float*)d_in[3];
  const float* bm = (const float*)d_in[4];
  const float* Wz = (const float*)d_in[5];
  const float* bz = (const float*)d_in[6];
  const float* Wr = (const float*)d_in[7];
  const float* br = (const float*)d_in[8];
  const float* Wh = (const float*)d_in[9];
  const float* bh = (const float*)d_in[10];
  float* out = (float*)d_out;

  const int N = in_sizes[0] / 128;
  const int E = in_sizes[2] / 2;
  const int* src = ei;
  const int* dst = ei + E;

  char* ws = (char*)d_ws;
  size_t o = 0;
  auto alloc = [&](size_t bytes) {
    char* p = ws + o;
    o = (o + bytes + 511) & ~(size_t)511;
    return p;
  };
  const int NB = (N + 255) >> 8;             // radix buckets
  const int nbch = (N + 1023) / 1024;        // fallback scan chunks
  int* bcntP  = (int*)alloc((size_t)NB * 16 * 4);
  int* gcurP  = (int*)alloc((size_t)NB * 16 * 4);
  int* bbases = (int*)alloc((size_t)(NB + 1) * 4);
  unsigned int* bin = (unsigned int*)alloc((size_t)E * 4);
  int* off    = (int*)alloc((size_t)(N + 1) * 4);
  int* cur    = (int*)alloc((size_t)(N + 1) * 4);   // fallback
  int* cnt    = (int*)alloc((size_t)N * 4);          // fallback
  int* psum   = (int*)alloc((size_t)nbch * 4);       // fallback
  void* eidx  = (void*)alloc((size_t)E * 4);
  f16* WtM    = (f16*)alloc((size_t)128 * 128 * 2);
  f16* WtZR   = (f16*)alloc((size_t)256 * 256 * 2);
  f16* WtH    = (f16*)alloc((size_t)128 * 256 * 2);
  f16* P0     = (f16*)alloc((size_t)N * 256 * 2);   // [nf|H] packed
  f16* X      = (f16*)alloc((size_t)N * 128 * 2);
  f16* AX     = (f16*)alloc((size_t)N * 128 * 2);
  f16* G      = (f16*)alloc((size_t)N * 128 * 2);
  f16* AP0    = (f16*)d_out;                        // dead before final write
  f16* Zh     = X;                                  // X dead after gather(X)
  f16* AG     = P0;                                 // P0 dead after gather(P0)

  const bool small = (N <= 65536);
  const int qblk = ((E + 3) / 4 + 255) / 256;

  // --- CSR build ---
  if (small) {
    zero_ints<<<(NB * 16 + 255) / 256, 256, 0, stream>>>(bcntP, NB * 16);
    bucket_hist<<<qblk, 256, 0, stream>>>(dst, bcntP, E, NB);
    bucket_scan<<<1, 256, 0, stream>>>(bcntP, bbases, gcurP, NB);
    partition_v2<<<(E + 4095) / 4096, 256, 0, stream>>>(src, dst, gcurP, bin, E, NB);
    bucket_sort<<<NB, 256, 0, stream>>>(bin, bbases, (unsigned short*)eidx, off, N, NB);
  } else {
    zero_ints<<<(N + 255) / 256, 256, 0, stream>>>(cnt, N);
    count_kernel<<<qblk, 256, 0, stream>>>(dst, cnt, E);
    scan_local<<<nbch, 1024, 0, stream>>>(cnt, off, psum, N);
    scan_carry<<<1, 1024, 0, stream>>>(psum, off, cur, nbch, N);
    scan_add<<<nbch, 1024, 0, stream>>>(off, cur, psum, N);
    fill_kernel<<<qblk, 256, 0, stream>>>(src, dst, cur, (int*)eidx, E);
  }

  // --- weight transpose + input pack ---
  wtrans_all<<<dim3(8, 4, 4), dim3(32, 8), 0, stream>>>(Wm, Wz, Wr, Wh, WtM, WtZR, WtH);
  const int pblk = (N * 64 + 255) / 256;
  pack_nfh<<<pblk, 256, 0, stream>>>(nf, H, P0, N);

  const int mblk = (N + 63) / 64;
  const int g256 = (N + 7) / 8;     // 2 nodes/wave, 4 waves/block
  const int g128 = (N + 15) / 16;   // 4 nodes/wave

  // --- AP0 = Agg([nf|H]) ---
  if (small)
    gather<256, unsigned short><<<g256, 256, 0, stream>>>(P0, off, (const unsigned short*)eidx, AP0, N);
  else
    gather<256, int><<<g256, 256, 0, stream>>>(P0, off, (const int*)eidx, AP0, N);

  // --- X = relu(Anf @ Wm + bm) ---
  gemm_mfma<1, 0><<<dim3(mblk, 1), 256, 0, stream>>>(
      AP0, 256, nullptr, 0, WtM, bm, nullptr, nullptr, nullptr, X, nullptr, nullptr, N);

  // --- AX = Agg(X) ---
  if (small)
    gather<128, unsigned short><<<g128, 256, 0, stream>>>(X, off, (const unsigned short*)eidx, AX, N);
  else
    gather<128, int><<<g128, 256, 0, stream>>>(X, off, (const int*)eidx, AX, N);

  // --- Z = sig([AX,AH]@Wz+bz), G = sig([AX,AH]@Wr+br)*H ---
  gemm_mfma<2, 1><<<dim3(mblk, 2), 256, 0, stream>>>(
      AX, 128, AP0 + 128, 256, WtZR, bz, br, H, nullptr, Zh, G, nullptr, N);

  // --- AG = Agg(G) ---
  if (small)
    gather<128, unsigned short><<<g128, 256, 0, stream>>>(G, off, (const unsigned short*)eidx, AG, N);
  else
    gather<128, int><<<g128, 256, 0, stream>>>(G, off, (const int*)eidx, AG, N);

  // --- out = Zh*H + (1-Zh)*tanh([AX,AG]@Wh + bh) ---
  gemm_mfma<2, 2><<<dim3(mblk, 1), 256, 0, stream>>>(
      AX, 128, AG, 128, WtH, bh, nullptr, H, Zh, nullptr, nullptr, out, N);
}